// Round 1
// baseline (246.186 us; speedup 1.0000x reference)
//
#include <hip/hip_runtime.h>

// ---------------------------------------------------------------------------
// MultiHeadAttention fused pipeline, fp16 MFMA, fp32 accumulation.
// B=2, N=2048, DIM=1024, H=16, hd=64.
// ---------------------------------------------------------------------------

#define BATCH 2
#define SEQ   2048
#define DIM_C 1024
#define NHEAD 16
#define HD    64
#define MTOT  (BATCH * SEQ)      // 4096
#define NQKV  (3 * DIM_C)        // 3072

typedef _Float16 h8 __attribute__((ext_vector_type(8)));
typedef _Float16 h4v __attribute__((ext_vector_type(4)));
typedef float    f4 __attribute__((ext_vector_type(4)));

__device__ __forceinline__ f4 mfma16(h8 a, h8 b, f4 c) {
  return __builtin_amdgcn_mfma_f32_16x16x32_f16(a, b, c, 0, 0, 0);
}

// ---------------------------------------------------------------------------
// fp32 -> fp16 conversion (vectorized float4 -> 4x f16)
// ---------------------------------------------------------------------------
__global__ void cvt_kernel(const float* __restrict__ src, _Float16* __restrict__ dst, int n4) {
  int stride = gridDim.x * blockDim.x;
  for (int i = blockIdx.x * blockDim.x + threadIdx.x; i < n4; i += stride) {
    float4 v = reinterpret_cast<const float4*>(src)[i];
    h4v o = {(_Float16)v.x, (_Float16)v.y, (_Float16)v.z, (_Float16)v.w};
    reinterpret_cast<h4v*>(dst)[i] = o;
  }
}

// ---------------------------------------------------------------------------
// RoPE cos/sin tables: [SEQ][32] each, fp32.
// cos[t, j] = cos(t * 10000^(-2j/64)), duplicated halves handled at use site.
// ---------------------------------------------------------------------------
__global__ void rope_table_kernel(float* __restrict__ cosT, float* __restrict__ sinT) {
  int idx = blockIdx.x * blockDim.x + threadIdx.x;   // SEQ*32 = 65536 exact
  int n = idx >> 5, j = idx & 31;
  float inv = powf(10000.0f, -(float)(2 * j) / 64.0f);
  float a = (float)n * inv;
  cosT[idx] = cosf(a);
  sinT[idx] = sinf(a);
}

// ---------------------------------------------------------------------------
// NT GEMM: C[M,N] = A[M,K] * Bm[N,K]^T   (both row-major, K contiguous)
// 128x128 tile, BK=32, 4 waves each computing a 64x64 sub-tile.
// LDS padded to 40 halves/row -> 2-way-max bank conflicts on ds_read_b128.
// ---------------------------------------------------------------------------
template <int OUT_F16>
__global__ __launch_bounds__(256) void gemm_nt(const _Float16* __restrict__ A,
                                               const _Float16* __restrict__ Bm,
                                               void* __restrict__ Cv,
                                               int M, int N, int K) {
  __shared__ _Float16 Ah[128][40];
  __shared__ _Float16 Bh[128][40];
  const int tid = threadIdx.x;
  const int wave = tid >> 6, lane = tid & 63;
  const int lr = lane & 15, lg = lane >> 4;
  const int m0 = blockIdx.y * 128, n0 = blockIdx.x * 128;
  const int wr = (wave >> 1) * 64, wc = (wave & 1) * 64;

  const f4 zf = {0.f, 0.f, 0.f, 0.f};
  f4 acc[4][4];
#pragma unroll
  for (int i = 0; i < 4; ++i)
#pragma unroll
    for (int j = 0; j < 4; ++j) acc[i][j] = zf;

  const int ksteps = K >> 5;
  for (int ks = 0; ks < ksteps; ++ks) {
    __syncthreads();
    const _Float16* As = A + (size_t)m0 * K + ks * 32;
    const _Float16* Bs = Bm + (size_t)n0 * K + ks * 32;
#pragma unroll
    for (int it = 0; it < 2; ++it) {
      int c = tid + it * 256;          // 512 chunks of 16B per operand
      int row = c >> 2, part = c & 3;
      *(h8*)&Ah[row][part * 8] = *(const h8*)(As + (size_t)row * K + part * 8);
      *(h8*)&Bh[row][part * 8] = *(const h8*)(Bs + (size_t)row * K + part * 8);
    }
    __syncthreads();

    h8 af[4], bf[4];
#pragma unroll
    for (int i = 0; i < 4; ++i) af[i] = *(const h8*)&Ah[wr + i * 16 + lr][lg * 8];
#pragma unroll
    for (int j = 0; j < 4; ++j) bf[j] = *(const h8*)&Bh[wc + j * 16 + lr][lg * 8];
#pragma unroll
    for (int i = 0; i < 4; ++i)
#pragma unroll
      for (int j = 0; j < 4; ++j) acc[i][j] = mfma16(af[i], bf[j], acc[i][j]);
  }

  // epilogue: C/D layout col = lane&15, row = (lane>>4)*4 + reg
#pragma unroll
  for (int i = 0; i < 4; ++i)
#pragma unroll
    for (int j = 0; j < 4; ++j)
#pragma unroll
      for (int r = 0; r < 4; ++r) {
        size_t row = (size_t)(m0 + wr + i * 16 + lg * 4 + r);
        int col = n0 + wc + j * 16 + lr;
        if (OUT_F16)
          ((_Float16*)Cv)[row * N + col] = (_Float16)acc[i][j][r];
        else
          ((float*)Cv)[row * N + col] = acc[i][j][r];
      }
}

// ---------------------------------------------------------------------------
// RoPE apply + scatter: qkv[4096][3072] f16 -> q,k,v [B][H][N][64] f16
// q additionally scaled by 1/sqrt(hd)=0.125 (folded into q so S=QK^T is final).
// One thread per (m, s, h, d<32) pair, handles d and d+32 together.
// ---------------------------------------------------------------------------
__global__ void rope_apply_kernel(const _Float16* __restrict__ qkv,
                                  const float* __restrict__ cosT,
                                  const float* __restrict__ sinT,
                                  _Float16* __restrict__ qh,
                                  _Float16* __restrict__ kh,
                                  _Float16* __restrict__ vh) {
  int idx = blockIdx.x * blockDim.x + threadIdx.x;  // 4096*3*16*32 = 6291456 exact
  int dlo = idx & 31;
  int t = idx >> 5;
  int h = t & 15;
  t >>= 4;
  int s = t % 3;
  int m = t / 3;               // 0..4095
  int b = m >> 11, n = m & 2047;

  const _Float16* src = qkv + (size_t)m * NQKV + s * DIM_C + h * HD;
  float x1 = (float)src[dlo];
  float x2 = (float)src[dlo + 32];

  float o1, o2;
  _Float16* dst;
  if (s == 2) {
    o1 = x1; o2 = x2; dst = vh;
  } else {
    float c = cosT[n * 32 + dlo];
    float sn = sinT[n * 32 + dlo];
    o1 = x1 * c - x2 * sn;   // d < 32:  q*cos - q[d+32]*sin
    o2 = x2 * c + x1 * sn;   // d >= 32: q*cos + q[d-32]*sin
    if (s == 0) { o1 *= 0.125f; o2 *= 0.125f; dst = qh; }
    else dst = kh;
  }
  size_t o = ((size_t)((b * NHEAD + h) * SEQ + n)) * HD;
  dst[o + dlo] = (_Float16)o1;
  dst[o + dlo + 32] = (_Float16)o2;
}

// ---------------------------------------------------------------------------
// Flash attention: grid = 32 (b,h) * 16 q-tiles of 128 rows. 4 waves/block,
// each wave owns 32 q-rows. KV tiles of 64 staged in LDS (V transposed).
// Online softmax; P round-trips through padded LDS for the PV A-operand.
// Output written as [B][N][H*64] f16 so the out-proj GEMM reads it directly.
// ---------------------------------------------------------------------------
__global__ __launch_bounds__(256) void attn_kernel(const _Float16* __restrict__ qh,
                                                   const _Float16* __restrict__ kh,
                                                   const _Float16* __restrict__ vh,
                                                   _Float16* __restrict__ aoh) {
  __shared__ _Float16 Kt[64][72];       // K tile  [kv][d]
  __shared__ _Float16 Vt[64][72];       // V tile transposed [d][kv]
  __shared__ _Float16 Pl[4][32][72];    // per-wave P [qrow][kv]

  const int tid = threadIdx.x, wave = tid >> 6, lane = tid & 63;
  const int lr = lane & 15, lg = lane >> 4;
  const int bh = blockIdx.x >> 4;       // 0..31
  const int qt = blockIdx.x & 15;
  const int b = bh >> 4, h = bh & 15;

  const _Float16* Qb = qh + (size_t)bh * SEQ * HD;
  const _Float16* Kb = kh + (size_t)bh * SEQ * HD;
  const _Float16* Vb = vh + (size_t)bh * SEQ * HD;
  const int q0 = qt * 128 + wave * 32;

  // Q fragments held in registers for the whole kernel
  h8 aq[2][2];
#pragma unroll
  for (int r2 = 0; r2 < 2; ++r2)
#pragma unroll
    for (int c = 0; c < 2; ++c)
      aq[r2][c] = *(const h8*)(Qb + (size_t)(q0 + r2 * 16 + lr) * HD + c * 32 + lg * 8);

  float m_s[2][4], l_s[2][4];
  const f4 zf = {0.f, 0.f, 0.f, 0.f};
  f4 acc[2][4];
#pragma unroll
  for (int r2 = 0; r2 < 2; ++r2) {
#pragma unroll
    for (int r = 0; r < 4; ++r) { m_s[r2][r] = -1e30f; l_s[r2][r] = 0.f; }
#pragma unroll
    for (int dt = 0; dt < 4; ++dt) acc[r2][dt] = zf;
  }

  for (int kt = 0; kt < SEQ / 64; ++kt) {
    __syncthreads();
    const _Float16* Ks = Kb + (size_t)kt * 64 * HD;
    const _Float16* Vs = Vb + (size_t)kt * 64 * HD;
#pragma unroll
    for (int it = 0; it < 2; ++it) {
      int c = tid + it * 256;            // 512 chunks of 16B
      int row = c >> 3, part = c & 7;
      *(h8*)&Kt[row][part * 8] = *(const h8*)(Ks + row * HD + part * 8);
      h8 vv = *(const h8*)(Vs + row * HD + part * 8);
#pragma unroll
      for (int j = 0; j < 8; ++j) Vt[part * 8 + j][row] = vv[j];
    }
    __syncthreads();

    // ---- S = Q K^T (scale pre-folded into Q), online softmax ----
#pragma unroll
    for (int r2 = 0; r2 < 2; ++r2) {
      f4 S[4];
#pragma unroll
      for (int ct = 0; ct < 4; ++ct) {
        h8 bk0 = *(const h8*)&Kt[ct * 16 + lr][lg * 8];
        h8 bk1 = *(const h8*)&Kt[ct * 16 + lr][32 + lg * 8];
        f4 z = mfma16(aq[r2][0], bk0, zf);
        S[ct] = mfma16(aq[r2][1], bk1, z);
      }
      float rmax[4], mn[4], al[4], rsum[4];
#pragma unroll
      for (int r = 0; r < 4; ++r) {
        float v = fmaxf(fmaxf(S[0][r], S[1][r]), fmaxf(S[2][r], S[3][r]));
        v = fmaxf(v, __shfl_xor(v, 1));
        v = fmaxf(v, __shfl_xor(v, 2));
        v = fmaxf(v, __shfl_xor(v, 4));
        v = fmaxf(v, __shfl_xor(v, 8));
        rmax[r] = v;
      }
#pragma unroll
      for (int r = 0; r < 4; ++r) {
        mn[r] = fmaxf(m_s[r2][r], rmax[r]);
        al[r] = __expf(m_s[r2][r] - mn[r]);
        m_s[r2][r] = mn[r];
        rsum[r] = 0.f;
      }
#pragma unroll
      for (int ct = 0; ct < 4; ++ct)
#pragma unroll
        for (int r = 0; r < 4; ++r) {
          float p = __expf(S[ct][r] - mn[r]);
          S[ct][r] = p;
          rsum[r] += p;
        }
#pragma unroll
      for (int r = 0; r < 4; ++r) {
        float v = rsum[r];
        v += __shfl_xor(v, 1);
        v += __shfl_xor(v, 2);
        v += __shfl_xor(v, 4);
        v += __shfl_xor(v, 8);
        l_s[r2][r] = l_s[r2][r] * al[r] + v;
      }
#pragma unroll
      for (int dt = 0; dt < 4; ++dt)
#pragma unroll
        for (int r = 0; r < 4; ++r) acc[r2][dt][r] = acc[r2][dt][r] * al[r];
      // store P (C-layout: row = lg*4+r, col = ct*16+lr)
#pragma unroll
      for (int ct = 0; ct < 4; ++ct)
#pragma unroll
        for (int r = 0; r < 4; ++r)
          Pl[wave][r2 * 16 + lg * 4 + r][ct * 16 + lr] = (_Float16)S[ct][r];
    }

    // ---- PV: acc += P * V ----
#pragma unroll
    for (int r2 = 0; r2 < 2; ++r2)
#pragma unroll
      for (int c = 0; c < 2; ++c) {
        h8 pa = *(const h8*)&Pl[wave][r2 * 16 + lr][c * 32 + lg * 8];
#pragma unroll
        for (int dt = 0; dt < 4; ++dt) {
          h8 vb = *(const h8*)&Vt[dt * 16 + lr][c * 32 + lg * 8];
          acc[r2][dt] = mfma16(pa, vb, acc[r2][dt]);
        }
      }
  }

  // ---- epilogue: normalize and write [B][N][H*64] f16 ----
#pragma unroll
  for (int r2 = 0; r2 < 2; ++r2)
#pragma unroll
    for (int dt = 0; dt < 4; ++dt)
#pragma unroll
      for (int r = 0; r < 4; ++r) {
        float o = acc[r2][dt][r] / l_s[r2][r];
        int row = q0 + r2 * 16 + lg * 4 + r;
        aoh[((size_t)(b * SEQ + row)) * DIM_C + h * HD + dt * 16 + lr] = (_Float16)o;
      }
}

// ---------------------------------------------------------------------------
// launch
// ---------------------------------------------------------------------------
extern "C" void kernel_launch(void* const* d_in, const int* in_sizes, int n_in,
                              void* d_out, int out_size, void* d_ws, size_t ws_size,
                              hipStream_t stream) {
  const float* x     = (const float*)d_in[0];
  const float* w_qkv = (const float*)d_in[1];
  const float* w_out = (const float*)d_in[2];
  float* out = (float*)d_out;

  char* w = (char*)d_ws;
  _Float16* xh    = (_Float16*)(w + 0);           //  8 MB  [4096][1024]
  _Float16* wqkvh = (_Float16*)(w + 8388608);     //  6 MB  [3072][1024]
  _Float16* wouth = (_Float16*)(w + 14680064);    //  2 MB  [1024][1024]
  _Float16* qkvh  = (_Float16*)(w + 16777216);    // 24 MB  [4096][3072]
  _Float16* qhp   = (_Float16*)(w + 41943040);    //  8 MB  [2][16][2048][64]
  _Float16* khp   = (_Float16*)(w + 50331648);    //  8 MB
  _Float16* vhp   = (_Float16*)(w + 58720256);    //  8 MB
  _Float16* aohp  = (_Float16*)(w + 67108864);    //  8 MB  [4096][1024]
  float*    cosT  = (float*)(w + 75497472);       // 256 KB [2048][32]
  float*    sinT  = (float*)(w + 75759616);       // 256 KB

  cvt_kernel<<<1024, 256, 0, stream>>>(x, xh, MTOT * DIM_C / 4);
  cvt_kernel<<<1024, 256, 0, stream>>>(w_qkv, wqkvh, NQKV * DIM_C / 4);
  cvt_kernel<<<512, 256, 0, stream>>>(w_out, wouth, DIM_C * DIM_C / 4);
  rope_table_kernel<<<SEQ * 32 / 256, 256, 0, stream>>>(cosT, sinT);

  gemm_nt<1><<<dim3(NQKV / 128, MTOT / 128), 256, 0, stream>>>(
      xh, wqkvh, (void*)qkvh, MTOT, NQKV, DIM_C);

  rope_apply_kernel<<<MTOT * 3 * NHEAD * 32 / 256, 256, 0, stream>>>(
      qkvh, cosT, sinT, qhp, khp, vhp);

  attn_kernel<<<32 * (SEQ / 128), 256, 0, stream>>>(qhp, khp, vhp, aohp);

  gemm_nt<0><<<dim3(DIM_C / 128, MTOT / 128), 256, 0, stream>>>(
      aohp, wouth, (void*)out, MTOT, DIM_C, DIM_C);
}

// Round 2
// 183.406 us; speedup vs baseline: 1.3423x; 1.3423x over previous
//
#include <hip/hip_runtime.h>

// ---------------------------------------------------------------------------
// MultiHeadAttention fused pipeline, fp16 MFMA, fp32 accumulation.
// B=2, N=2048, DIM=1024, H=16, hd=64.
// ---------------------------------------------------------------------------

#define BATCH 2
#define SEQ   2048
#define DIM_C 1024
#define NHEAD 16
#define HD    64
#define MTOT  (BATCH * SEQ)      // 4096
#define NQKV  (3 * DIM_C)        // 3072

typedef _Float16 h8 __attribute__((ext_vector_type(8)));
typedef _Float16 h4v __attribute__((ext_vector_type(4)));
typedef float    f4 __attribute__((ext_vector_type(4)));

__device__ __forceinline__ f4 mfma16(h8 a, h8 b, f4 c) {
  return __builtin_amdgcn_mfma_f32_16x16x32_f16(a, b, c, 0, 0, 0);
}

// ---------------------------------------------------------------------------
// fp32 -> fp16 conversion (vectorized float4 -> 4x f16)
// ---------------------------------------------------------------------------
__global__ void cvt_kernel(const float* __restrict__ src, _Float16* __restrict__ dst, int n4) {
  int stride = gridDim.x * blockDim.x;
  for (int i = blockIdx.x * blockDim.x + threadIdx.x; i < n4; i += stride) {
    float4 v = reinterpret_cast<const float4*>(src)[i];
    h4v o = {(_Float16)v.x, (_Float16)v.y, (_Float16)v.z, (_Float16)v.w};
    reinterpret_cast<h4v*>(dst)[i] = o;
  }
}

// ---------------------------------------------------------------------------
// RoPE cos/sin tables: [SEQ][32] each, fp32.
// ---------------------------------------------------------------------------
__global__ void rope_table_kernel(float* __restrict__ cosT, float* __restrict__ sinT) {
  int idx = blockIdx.x * blockDim.x + threadIdx.x;   // SEQ*32 = 65536 exact
  int n = idx >> 5, j = idx & 31;
  float inv = powf(10000.0f, -(float)(2 * j) / 64.0f);
  float a = (float)n * inv;
  cosT[idx] = cosf(a);
  sinT[idx] = sinf(a);
}

// ---------------------------------------------------------------------------
// NT GEMM: C[M,N] = A[M,K] * Bm[N,K]^T  (unchanged from round 1 — works)
// ---------------------------------------------------------------------------
template <int OUT_F16>
__global__ __launch_bounds__(256) void gemm_nt(const _Float16* __restrict__ A,
                                               const _Float16* __restrict__ Bm,
                                               void* __restrict__ Cv,
                                               int M, int N, int K) {
  __shared__ _Float16 Ah[128][40];
  __shared__ _Float16 Bh[128][40];
  const int tid = threadIdx.x;
  const int wave = tid >> 6, lane = tid & 63;
  const int lr = lane & 15, lg = lane >> 4;
  const int m0 = blockIdx.y * 128, n0 = blockIdx.x * 128;
  const int wr = (wave >> 1) * 64, wc = (wave & 1) * 64;

  const f4 zf = {0.f, 0.f, 0.f, 0.f};
  f4 acc[4][4];
#pragma unroll
  for (int i = 0; i < 4; ++i)
#pragma unroll
    for (int j = 0; j < 4; ++j) acc[i][j] = zf;

  const int ksteps = K >> 5;
  for (int ks = 0; ks < ksteps; ++ks) {
    __syncthreads();
    const _Float16* As = A + (size_t)m0 * K + ks * 32;
    const _Float16* Bs = Bm + (size_t)n0 * K + ks * 32;
#pragma unroll
    for (int it = 0; it < 2; ++it) {
      int c = tid + it * 256;          // 512 chunks of 16B per operand
      int row = c >> 2, part = c & 3;
      *(h8*)&Ah[row][part * 8] = *(const h8*)(As + (size_t)row * K + part * 8);
      *(h8*)&Bh[row][part * 8] = *(const h8*)(Bs + (size_t)row * K + part * 8);
    }
    __syncthreads();

    h8 af[4], bf[4];
#pragma unroll
    for (int i = 0; i < 4; ++i) af[i] = *(const h8*)&Ah[wr + i * 16 + lr][lg * 8];
#pragma unroll
    for (int j = 0; j < 4; ++j) bf[j] = *(const h8*)&Bh[wc + j * 16 + lr][lg * 8];
#pragma unroll
    for (int i = 0; i < 4; ++i)
#pragma unroll
      for (int j = 0; j < 4; ++j) acc[i][j] = mfma16(af[i], bf[j], acc[i][j]);
  }

#pragma unroll
  for (int i = 0; i < 4; ++i)
#pragma unroll
    for (int j = 0; j < 4; ++j)
#pragma unroll
      for (int r = 0; r < 4; ++r) {
        size_t row = (size_t)(m0 + wr + i * 16 + lg * 4 + r);
        int col = n0 + wc + j * 16 + lr;
        if (OUT_F16)
          ((_Float16*)Cv)[row * N + col] = (_Float16)acc[i][j][r];
        else
          ((float*)Cv)[row * N + col] = acc[i][j][r];
      }
}

// ---------------------------------------------------------------------------
// RoPE apply + scatter: qkv[4096][3072] f16 -> q,k,v [B][H][N][64] f16
// q pre-scaled by 1/sqrt(hd)=0.125.
// ---------------------------------------------------------------------------
__global__ void rope_apply_kernel(const _Float16* __restrict__ qkv,
                                  const float* __restrict__ cosT,
                                  const float* __restrict__ sinT,
                                  _Float16* __restrict__ qh,
                                  _Float16* __restrict__ kh,
                                  _Float16* __restrict__ vh) {
  int idx = blockIdx.x * blockDim.x + threadIdx.x;  // 4096*3*16*32 exact
  int dlo = idx & 31;
  int t = idx >> 5;
  int h = t & 15;
  t >>= 4;
  int s = t % 3;
  int m = t / 3;               // 0..4095
  int b = m >> 11, n = m & 2047;

  const _Float16* src = qkv + (size_t)m * NQKV + s * DIM_C + h * HD;
  float x1 = (float)src[dlo];
  float x2 = (float)src[dlo + 32];

  float o1, o2;
  _Float16* dst;
  if (s == 2) {
    o1 = x1; o2 = x2; dst = vh;
  } else {
    float c = cosT[n * 32 + dlo];
    float sn = sinT[n * 32 + dlo];
    o1 = x1 * c - x2 * sn;
    o2 = x2 * c + x1 * sn;
    if (s == 0) { o1 *= 0.125f; o2 *= 0.125f; dst = qh; }
    else dst = kh;
  }
  size_t o = ((size_t)((b * NHEAD + h) * SEQ + n)) * HD;
  dst[o + dlo] = (_Float16)o1;
  dst[o + dlo + 32] = (_Float16)o2;
}

// ---------------------------------------------------------------------------
// V transpose: [bh][2048][64] -> [bh][64][2048].
// Block: 256 threads = 64 d-lanes x 4 n-octets; covers 32 n per block.
// Reads coalesced (lanes span d); writes h8 (16B granule), 4 warps of a block
// cover a full 64B line per d-row.
// ---------------------------------------------------------------------------
__global__ void vtrans_kernel(const _Float16* __restrict__ v, _Float16* __restrict__ vt) {
  int blk = blockIdx.x;            // 32 bh * 64 tiles
  int bh = blk >> 6, nt = blk & 63;
  int d = threadIdx.x & 63, w = threadIdx.x >> 6;
  int n0 = nt * 32 + w * 8;
  const _Float16* src = v + (size_t)bh * SEQ * HD;
  _Float16* dst = vt + ((size_t)bh * HD + d) * SEQ;
  h8 o;
#pragma unroll
  for (int j = 0; j < 8; ++j) o[j] = src[(size_t)(n0 + j) * HD + d];
  *(h8*)(dst + n0) = o;
}

// ---------------------------------------------------------------------------
// Flash attention v2: swapped QK^T (q = lane&15 lane-local), PV^T, V^T staged
// coalesced from pre-transposed global V. All LDS tiles split into 32-column
// halves at stride 40 -> conflict-free b128 per 8-lane clock group.
// Output written as [B][N][H*64] f16 for the out-proj GEMM.
// ---------------------------------------------------------------------------
__global__ __launch_bounds__(256) void attn_kernel(const _Float16* __restrict__ qh,
                                                   const _Float16* __restrict__ kh,
                                                   const _Float16* __restrict__ vt,
                                                   _Float16* __restrict__ aoh) {
  __shared__ _Float16 KtA[64][40], KtB[64][40];        // K tile [kv][d<32 | d>=32]
  __shared__ _Float16 VtA[64][40], VtB[64][40];        // V^T tile [d][kv<32 | kv>=32]
  __shared__ _Float16 PlA[4][32][40], PlB[4][32][40];  // per-wave P [q][k<32 | k>=32]

  const int tid = threadIdx.x, wave = tid >> 6, lane = tid & 63;
  const int lr = lane & 15, lg = lane >> 4;
  const int bh = blockIdx.x >> 4;       // 0..31
  const int qt = blockIdx.x & 15;
  const int b = bh >> 4, h = bh & 15;

  const _Float16* Qb = qh + (size_t)bh * SEQ * HD;
  const _Float16* Kb = kh + (size_t)bh * SEQ * HD;
  const _Float16* Vb = vt + (size_t)bh * HD * SEQ;     // [64][2048]
  const int q0 = qt * 128 + wave * 32;

  // Q frags (Y operand): row=lr -> q, k-cols = d
  h8 aq[2][2];
#pragma unroll
  for (int r2 = 0; r2 < 2; ++r2)
#pragma unroll
    for (int c = 0; c < 2; ++c)
      aq[r2][c] = *(const h8*)(Qb + (size_t)(q0 + r2 * 16 + lr) * HD + c * 32 + lg * 8);

  float m_s[2] = {-1e30f, -1e30f}, l_s[2] = {0.f, 0.f};
  const f4 zf = {0.f, 0.f, 0.f, 0.f};
  f4 acc[2][4];                        // [r2][dt]: col q=lr, rows d=dt*16+lg*4+r
#pragma unroll
  for (int r2 = 0; r2 < 2; ++r2)
#pragma unroll
    for (int dt = 0; dt < 4; ++dt) acc[r2][dt] = zf;

  for (int kt = 0; kt < SEQ / 64; ++kt) {
    __syncthreads();
    {
      const _Float16* Ks = Kb + (size_t)kt * 64 * HD;
      const _Float16* Vs = Vb + kt * 64;
#pragma unroll
      for (int it = 0; it < 2; ++it) {
        int c = tid + it * 256;        // 512 chunks of 16B each for K and V^T
        int row = c >> 3, part = c & 7;
        h8 kv8 = *(const h8*)(Ks + (size_t)row * HD + part * 8);
        h8 vv8 = *(const h8*)(Vs + (size_t)row * SEQ + part * 8);
        if (part < 4) {
          *(h8*)&KtA[row][part * 8] = kv8;
          *(h8*)&VtA[row][part * 8] = vv8;
        } else {
          *(h8*)&KtB[row][(part - 4) * 8] = kv8;
          *(h8*)&VtB[row][(part - 4) * 8] = vv8;
        }
      }
    }
    __syncthreads();

    // hoisted K frags (X operand): rows k = ct*16+lr, d-chunk c
    h8 bk[4][2];
#pragma unroll
    for (int ct = 0; ct < 4; ++ct) {
      bk[ct][0] = *(const h8*)&KtA[ct * 16 + lr][lg * 8];
      bk[ct][1] = *(const h8*)&KtB[ct * 16 + lr][lg * 8];
    }
    // hoisted V^T frags (X operand): rows d = dt*16+lr, k-chunk c
    h8 vb[4][2];
#pragma unroll
    for (int dt = 0; dt < 4; ++dt) {
      vb[dt][0] = *(const h8*)&VtA[dt * 16 + lr][lg * 8];
      vb[dt][1] = *(const h8*)&VtB[dt * 16 + lr][lg * 8];
    }

    // ---- S^T = K Q^T per q sub-tile; lane holds q=lr, k = ct*16+lg*4+r ----
#pragma unroll
    for (int r2 = 0; r2 < 2; ++r2) {
      f4 St[4];
#pragma unroll
      for (int ct = 0; ct < 4; ++ct) {
        f4 z = mfma16(bk[ct][0], aq[r2][0], zf);
        St[ct] = mfma16(bk[ct][1], aq[r2][1], z);
      }
      float pmax = -1e30f;
#pragma unroll
      for (int ct = 0; ct < 4; ++ct)
#pragma unroll
        for (int r = 0; r < 4; ++r) pmax = fmaxf(pmax, St[ct][r]);
      pmax = fmaxf(pmax, __shfl_xor(pmax, 16));
      pmax = fmaxf(pmax, __shfl_xor(pmax, 32));

      float mn = fmaxf(m_s[r2], pmax);
      float al = __expf(m_s[r2] - mn);
      m_s[r2] = mn;

      float rsum = 0.f;
#pragma unroll
      for (int ct = 0; ct < 4; ++ct)
#pragma unroll
        for (int r = 0; r < 4; ++r) {
          float p = __expf(St[ct][r] - mn);
          St[ct][r] = p;
          rsum += p;
        }
      rsum += __shfl_xor(rsum, 16);
      rsum += __shfl_xor(rsum, 32);
      l_s[r2] = l_s[r2] * al + rsum;

#pragma unroll
      for (int dt = 0; dt < 4; ++dt)
#pragma unroll
        for (int r = 0; r < 4; ++r) acc[r2][dt][r] *= al;

      // pack P: lane's 4 regs are k-contiguous -> one b64 store per ct
#pragma unroll
      for (int ct = 0; ct < 4; ++ct) {
        h4v pk = {(_Float16)St[ct][0], (_Float16)St[ct][1],
                  (_Float16)St[ct][2], (_Float16)St[ct][3]};
        if (ct < 2)
          *(h4v*)&PlA[wave][r2 * 16 + lr][ct * 16 + lg * 4] = pk;
        else
          *(h4v*)&PlB[wave][r2 * 16 + lr][(ct - 2) * 16 + lg * 4] = pk;
      }
    }

    // ---- acc^T += V^T P^T : D[d][q], col q=lr lane-local ----
#pragma unroll
    for (int r2 = 0; r2 < 2; ++r2)
#pragma unroll
      for (int c = 0; c < 2; ++c) {
        h8 pa = (c == 0) ? *(const h8*)&PlA[wave][r2 * 16 + lr][lg * 8]
                         : *(const h8*)&PlB[wave][r2 * 16 + lr][lg * 8];
#pragma unroll
        for (int dt = 0; dt < 4; ++dt)
          acc[r2][dt] = mfma16(vb[dt][c], pa, acc[r2][dt]);
      }
  }

  // ---- epilogue: divide by l (lane-local), pack h4, write [B][N][H*64] ----
#pragma unroll
  for (int r2 = 0; r2 < 2; ++r2) {
    float inv = 1.0f / l_s[r2];
    int q = q0 + r2 * 16 + lr;
#pragma unroll
    for (int dt = 0; dt < 4; ++dt) {
      h4v o = {(_Float16)(acc[r2][dt][0] * inv), (_Float16)(acc[r2][dt][1] * inv),
               (_Float16)(acc[r2][dt][2] * inv), (_Float16)(acc[r2][dt][3] * inv)};
      *(h4v*)&aoh[((size_t)(b * SEQ + q)) * DIM_C + h * HD + dt * 16 + lg * 4] = o;
    }
  }
}

// ---------------------------------------------------------------------------
// launch
// ---------------------------------------------------------------------------
extern "C" void kernel_launch(void* const* d_in, const int* in_sizes, int n_in,
                              void* d_out, int out_size, void* d_ws, size_t ws_size,
                              hipStream_t stream) {
  const float* x     = (const float*)d_in[0];
  const float* w_qkv = (const float*)d_in[1];
  const float* w_out = (const float*)d_in[2];
  float* out = (float*)d_out;

  char* w = (char*)d_ws;
  _Float16* xh    = (_Float16*)(w + 0);           //  8 MB  [4096][1024]
  _Float16* wqkvh = (_Float16*)(w + 8388608);     //  6 MB  [3072][1024]
  _Float16* wouth = (_Float16*)(w + 14680064);    //  2 MB  [1024][1024]
  _Float16* qkvh  = (_Float16*)(w + 16777216);    // 24 MB  [4096][3072] (dead after rope)
  _Float16* qhp   = (_Float16*)(w + 41943040);    //  8 MB  [2][16][2048][64]
  _Float16* khp   = (_Float16*)(w + 50331648);    //  8 MB
  _Float16* vhp   = (_Float16*)(w + 58720256);    //  8 MB
  _Float16* aohp  = (_Float16*)(w + 67108864);    //  8 MB  [4096][1024]
  float*    cosT  = (float*)(w + 75497472);       // 256 KB [2048][32]
  float*    sinT  = (float*)(w + 75759616);       // 256 KB
  _Float16* vtp   = (_Float16*)(w + 16777216);    //  8 MB  [2][16][64][2048] (reuses qkvh)

  cvt_kernel<<<1024, 256, 0, stream>>>(x, xh, MTOT * DIM_C / 4);
  cvt_kernel<<<1024, 256, 0, stream>>>(w_qkv, wqkvh, NQKV * DIM_C / 4);
  cvt_kernel<<<512, 256, 0, stream>>>(w_out, wouth, DIM_C * DIM_C / 4);
  rope_table_kernel<<<SEQ * 32 / 256, 256, 0, stream>>>(cosT, sinT);

  gemm_nt<1><<<dim3(NQKV / 128, MTOT / 128), 256, 0, stream>>>(
      xh, wqkvh, (void*)qkvh, MTOT, NQKV, DIM_C);

  rope_apply_kernel<<<MTOT * 3 * NHEAD * 32 / 256, 256, 0, stream>>>(
      qkvh, cosT, sinT, qhp, khp, vhp);

  vtrans_kernel<<<32 * 64, 256, 0, stream>>>(vhp, vtp);   // qkvh region now dead

  attn_kernel<<<32 * (SEQ / 128), 256, 0, stream>>>(qhp, khp, vtp, aohp);

  gemm_nt<0><<<dim3(DIM_C / 128, MTOT / 128), 256, 0, stream>>>(
      aohp, wouth, (void*)out, MTOT, DIM_C, DIM_C);
}

// Round 3
// 156.695 us; speedup vs baseline: 1.5711x; 1.1705x over previous
//
#include <hip/hip_runtime.h>
#include <stdint.h>

// ---------------------------------------------------------------------------
// MultiHeadAttention fused pipeline, fp16 MFMA, fp32 accumulation.
// B=2, N=2048, DIM=1024, H=16, hd=64.
// ---------------------------------------------------------------------------

#define BATCH 2
#define SEQ   2048
#define DIM_C 1024
#define NHEAD 16
#define HD    64
#define MTOT  (BATCH * SEQ)      // 4096
#define NQKV  (3 * DIM_C)        // 3072
// 0.125 * log2(e): QK^T lands in log2 domain -> exp2 (single v_exp_f32)
#define QSCALE 0.1803368801111204f

typedef _Float16 h8 __attribute__((ext_vector_type(8)));
typedef _Float16 h4v __attribute__((ext_vector_type(4)));
typedef float    f4 __attribute__((ext_vector_type(4)));

#if __has_builtin(__builtin_amdgcn_exp2f)
#define EXP2(x) __builtin_amdgcn_exp2f(x)
#else
#define EXP2(x) exp2f(x)
#endif

__device__ __forceinline__ f4 mfma16(h8 a, h8 b, f4 c) {
  return __builtin_amdgcn_mfma_f32_16x16x32_f16(a, b, c, 0, 0, 0);
}

// async global->LDS, 16B per lane; LDS dest must be linear in lane order.
__device__ __forceinline__ void gload16(const _Float16* g, _Float16* l) {
  __builtin_amdgcn_global_load_lds(
      (const __attribute__((address_space(1))) void*)g,
      (__attribute__((address_space(3))) void*)l, 16, 0, 0);
}

// ---------------------------------------------------------------------------
// fp32 -> fp16 conversion (vectorized float4 -> 4x f16)
// ---------------------------------------------------------------------------
__global__ void cvt_kernel(const float* __restrict__ src, _Float16* __restrict__ dst, int n4) {
  int stride = gridDim.x * blockDim.x;
  for (int i = blockIdx.x * blockDim.x + threadIdx.x; i < n4; i += stride) {
    float4 v = reinterpret_cast<const float4*>(src)[i];
    h4v o = {(_Float16)v.x, (_Float16)v.y, (_Float16)v.z, (_Float16)v.w};
    reinterpret_cast<h4v*>(dst)[i] = o;
  }
}

// ---------------------------------------------------------------------------
// RoPE cos/sin tables: [SEQ][32] each, fp32.
// ---------------------------------------------------------------------------
__global__ void rope_table_kernel(float* __restrict__ cosT, float* __restrict__ sinT) {
  int idx = blockIdx.x * blockDim.x + threadIdx.x;   // SEQ*32 = 65536 exact
  int n = idx >> 5, j = idx & 31;
  float inv = powf(10000.0f, -(float)(2 * j) / 64.0f);
  float a = (float)n * inv;
  cosT[idx] = cosf(a);
  sinT[idx] = sinf(a);
}

// ---------------------------------------------------------------------------
// NT GEMM: C[M,N] = A[M,K] * Bm[N,K]^T. 128x128 tile, BK=32.
// Double-buffered LDS via global_load_lds (16B), one barrier per K-step.
// ---------------------------------------------------------------------------
template <int OUT_F16>
__global__ __launch_bounds__(256) void gemm_nt(const _Float16* __restrict__ A,
                                               const _Float16* __restrict__ Bm,
                                               void* __restrict__ Cv,
                                               int M, int N, int K) {
  __shared__ _Float16 Ah[2][128 * 32];
  __shared__ _Float16 Bh[2][128 * 32];
  const int tid = threadIdx.x;
  const int wave = tid >> 6, lane = tid & 63;
  const int lr = lane & 15, lg = lane >> 4;
  const int m0 = blockIdx.y * 128, n0 = blockIdx.x * 128;
  const int wr = (wave >> 1) * 64, wc = (wave & 1) * 64;

  const f4 zf = {0.f, 0.f, 0.f, 0.f};
  f4 acc[4][4];
#pragma unroll
  for (int i = 0; i < 4; ++i)
#pragma unroll
    for (int j = 0; j < 4; ++j) acc[i][j] = zf;

  const _Float16* Ab = A + (size_t)m0 * K;
  const _Float16* Bb = Bm + (size_t)n0 * K;

  auto stage = [&](int ks, int bi) {
#pragma unroll
    for (int it = 0; it < 2; ++it) {
      int c = tid + it * 256;          // 512 chunks of 16B per operand
      int row = c >> 2, part = c & 3;
      gload16(Ab + (size_t)row * K + ks * 32 + part * 8, &Ah[bi][c * 8]);
      gload16(Bb + (size_t)row * K + ks * 32 + part * 8, &Bh[bi][c * 8]);
    }
  };

  stage(0, 0);
  const int ksteps = K >> 5;
  for (int ks = 0; ks < ksteps; ++ks) {
    __syncthreads();                   // drains own vmcnt -> stage(ks) visible
    int cur = ks & 1;
    if (ks + 1 < ksteps) stage(ks + 1, cur ^ 1);

    h8 af[4], bf[4];
#pragma unroll
    for (int i = 0; i < 4; ++i) af[i] = *(const h8*)&Ah[cur][(wr + i * 16 + lr) * 32 + lg * 8];
#pragma unroll
    for (int j = 0; j < 4; ++j) bf[j] = *(const h8*)&Bh[cur][(wc + j * 16 + lr) * 32 + lg * 8];
#pragma unroll
    for (int i = 0; i < 4; ++i)
#pragma unroll
      for (int j = 0; j < 4; ++j) acc[i][j] = mfma16(af[i], bf[j], acc[i][j]);
  }

#pragma unroll
  for (int i = 0; i < 4; ++i)
#pragma unroll
    for (int j = 0; j < 4; ++j)
#pragma unroll
      for (int r = 0; r < 4; ++r) {
        size_t row = (size_t)(m0 + wr + i * 16 + lg * 4 + r);
        int col = n0 + wc + j * 16 + lr;
        if (OUT_F16)
          ((_Float16*)Cv)[row * N + col] = (_Float16)acc[i][j][r];
        else
          ((float*)Cv)[row * N + col] = acc[i][j][r];
      }
}

// ---------------------------------------------------------------------------
// RoPE apply + scatter, vectorized h8: qkv[4096][3072] -> q,k,v [B][H][N][64].
// q pre-scaled by 0.125*log2(e) so QK^T is in log2 domain for exp2 softmax.
// ---------------------------------------------------------------------------
__global__ void rope_apply_kernel(const _Float16* __restrict__ qkv,
                                  const float* __restrict__ cosT,
                                  const float* __restrict__ sinT,
                                  _Float16* __restrict__ qh,
                                  _Float16* __restrict__ kh,
                                  _Float16* __restrict__ vh) {
  int idx = blockIdx.x * blockDim.x + threadIdx.x;  // 4096*3*16*4 = 786432 exact
  int c8 = idx & 3;            // 8-halves chunk within lower 32 dims
  int t = idx >> 2;
  int h = t & 15;
  t >>= 4;
  int s = t % 3;
  int m = t / 3;               // 0..4095
  int b = m >> 11, n = m & 2047;

  const _Float16* src = qkv + (size_t)m * NQKV + s * DIM_C + h * HD + c8 * 8;
  h8 x1 = *(const h8*)src;
  h8 x2 = *(const h8*)(src + 32);
  size_t o = ((size_t)((b * NHEAD + h) * SEQ + n)) * HD + c8 * 8;

  if (s == 2) {
    *(h8*)(vh + o) = x1;
    *(h8*)(vh + o + 32) = x2;
  } else {
    f4 cs0 = *(const f4*)(cosT + n * 32 + c8 * 8);
    f4 cs1 = *(const f4*)(cosT + n * 32 + c8 * 8 + 4);
    f4 sn0 = *(const f4*)(sinT + n * 32 + c8 * 8);
    f4 sn1 = *(const f4*)(sinT + n * 32 + c8 * 8 + 4);
    float scl = (s == 0) ? QSCALE : 1.0f;
    _Float16* dst = (s == 0) ? qh : kh;
    h8 o1, o2;
#pragma unroll
    for (int j = 0; j < 8; ++j) {
      float cv = (j < 4) ? cs0[j] : cs1[j - 4];
      float sv = (j < 4) ? sn0[j] : sn1[j - 4];
      float a1 = (float)x1[j], a2 = (float)x2[j];
      o1[j] = (_Float16)((a1 * cv - a2 * sv) * scl);
      o2[j] = (_Float16)((a2 * cv + a1 * sv) * scl);
    }
    *(h8*)(dst + o) = o1;
    *(h8*)(dst + o + 32) = o2;
  }
}

// ---------------------------------------------------------------------------
// V transpose: [bh][2048][64] -> [bh][64][2048].
// ---------------------------------------------------------------------------
__global__ void vtrans_kernel(const _Float16* __restrict__ v, _Float16* __restrict__ vt) {
  int blk = blockIdx.x;            // 32 bh * 64 tiles
  int bh = blk >> 6, nt = blk & 63;
  int d = threadIdx.x & 63, w = threadIdx.x >> 6;
  int n0 = nt * 32 + w * 8;
  const _Float16* src = v + (size_t)bh * SEQ * HD;
  _Float16* dst = vt + ((size_t)bh * HD + d) * SEQ;
  h8 o;
#pragma unroll
  for (int j = 0; j < 8; ++j) o[j] = src[(size_t)(n0 + j) * HD + d];
  *(h8*)(dst + n0) = o;
}

// ---------------------------------------------------------------------------
// Flash attention v3: swapped QK^T (q lane-local), PV^T, exp2 softmax with
// defer-max (THR=8 in log2 domain). K/V^T double-buffered in LDS via
// global_load_lds with XOR-involution chunk swizzle (source + read swizzled,
// LDS dest linear). One __syncthreads per KV tile; stage(t+1) hides under
// softmax+PV of tile t.
// ---------------------------------------------------------------------------
__global__ __launch_bounds__(256) void attn_kernel(const _Float16* __restrict__ qh,
                                                   const _Float16* __restrict__ kh,
                                                   const _Float16* __restrict__ vt,
                                                   _Float16* __restrict__ aoh) {
  __shared__ _Float16 Kt[2][64 * 64];                  // [kv][d], rows 128B, swizzled
  __shared__ _Float16 Vt[2][64 * 64];                  // [d][kv], rows 128B, swizzled
  __shared__ _Float16 PlA[4][32][40], PlB[4][32][40];  // per-wave P [q][k<32 | k>=32]

  const int tid = threadIdx.x, wave = tid >> 6, lane = tid & 63;
  const int lr = lane & 15, lg = lane >> 4;
  const int bh = blockIdx.x >> 4;       // 0..31
  const int qt = blockIdx.x & 15;
  const int b = bh >> 4, h = bh & 15;

  const _Float16* Qb = qh + (size_t)bh * SEQ * HD;
  const _Float16* Kb = kh + (size_t)bh * SEQ * HD;
  const _Float16* Vb = vt + (size_t)bh * HD * SEQ;     // [64][2048]
  const int q0 = qt * 128 + wave * 32;

  // swizzled read chunk offsets (halves): chunk g=hf*4+lg, involution g^(lr&7)
  const int cOf0 = ((lg) ^ (lr & 7)) * 8;
  const int cOf1 = ((4 + lg) ^ (lr & 7)) * 8;

  // Q frags (Y operand): row=lr -> q, k-cols = d
  h8 aq[2][2];
#pragma unroll
  for (int r2 = 0; r2 < 2; ++r2)
#pragma unroll
    for (int c = 0; c < 2; ++c)
      aq[r2][c] = *(const h8*)(Qb + (size_t)(q0 + r2 * 16 + lr) * HD + c * 32 + lg * 8);

  float m_s[2] = {-1e30f, -1e30f}, l_s[2] = {0.f, 0.f};
  const f4 zf = {0.f, 0.f, 0.f, 0.f};
  f4 acc[2][4];                        // [r2][dt]: col q=lr, rows d=dt*16+lg*4+r
#pragma unroll
  for (int r2 = 0; r2 < 2; ++r2)
#pragma unroll
    for (int dt = 0; dt < 4; ++dt) acc[r2][dt] = zf;

  // stage: LDS linear at c*16B, global source chunk XOR-swizzled
  auto stage = [&](int kt, int bi) {
    const _Float16* Ks = Kb + (size_t)kt * 64 * HD;
    const _Float16* Vs = Vb + kt * 64;
#pragma unroll
    for (int it = 0; it < 2; ++it) {
      int c = tid + it * 256;          // 512 chunks of 16B per tile
      int row = c >> 3, part = c & 7;
      int sp = part ^ (row & 7);
      gload16(Ks + (size_t)row * HD + sp * 8, &Kt[bi][c * 8]);
      gload16(Vs + (size_t)row * SEQ + sp * 8, &Vt[bi][c * 8]);
    }
  };

  stage(0, 0);
  for (int kt = 0; kt < SEQ / 64; ++kt) {
    __syncthreads();                   // drains vmcnt -> stage(kt) visible
    const int cur = kt & 1;
    if (kt + 1 < SEQ / 64) stage(kt + 1, cur ^ 1);

    const _Float16* Kbuf = &Kt[cur][0];
    const _Float16* Vbuf = &Vt[cur][0];
    h8 bk[4][2], vb[4][2];
#pragma unroll
    for (int ct = 0; ct < 4; ++ct) {
      bk[ct][0] = *(const h8*)(Kbuf + (ct * 16 + lr) * 64 + cOf0);
      bk[ct][1] = *(const h8*)(Kbuf + (ct * 16 + lr) * 64 + cOf1);
    }
#pragma unroll
    for (int dt = 0; dt < 4; ++dt) {
      vb[dt][0] = *(const h8*)(Vbuf + (dt * 16 + lr) * 64 + cOf0);
      vb[dt][1] = *(const h8*)(Vbuf + (dt * 16 + lr) * 64 + cOf1);
    }

    // ---- S^T = K Q^T (log2 domain); lane holds q=lr, k = ct*16+lg*4+r ----
#pragma unroll
    for (int r2 = 0; r2 < 2; ++r2) {
      f4 St[4];
      __builtin_amdgcn_s_setprio(1);
#pragma unroll
      for (int ct = 0; ct < 4; ++ct) {
        f4 z = mfma16(bk[ct][0], aq[r2][0], zf);
        St[ct] = mfma16(bk[ct][1], aq[r2][1], z);
      }
      __builtin_amdgcn_s_setprio(0);
      float pmax = fmaxf(fmaxf(fmaxf(St[0][0], St[0][1]), fmaxf(St[0][2], St[0][3])),
                         fmaxf(fmaxf(St[1][0], St[1][1]), fmaxf(St[1][2], St[1][3])));
      float pmax2 = fmaxf(fmaxf(fmaxf(St[2][0], St[2][1]), fmaxf(St[2][2], St[2][3])),
                          fmaxf(fmaxf(St[3][0], St[3][1]), fmaxf(St[3][2], St[3][3])));
      pmax = fmaxf(pmax, pmax2);
      pmax = fmaxf(pmax, __shfl_xor(pmax, 16));
      pmax = fmaxf(pmax, __shfl_xor(pmax, 32));

      // defer-max: only rescale when max grows by > 8 (factor 256)
      bool grow = pmax > m_s[r2] + 8.f;
      if (__ballot(grow)) {
        float mn = fmaxf(m_s[r2], pmax);
        float al = EXP2(m_s[r2] - mn);
        m_s[r2] = mn;
        l_s[r2] *= al;
#pragma unroll
        for (int dt = 0; dt < 4; ++dt)
#pragma unroll
          for (int r = 0; r < 4; ++r) acc[r2][dt][r] *= al;
      }

      float rsum = 0.f;
#pragma unroll
      for (int ct = 0; ct < 4; ++ct)
#pragma unroll
        for (int r = 0; r < 4; ++r) {
          float p = EXP2(St[ct][r] - m_s[r2]);
          St[ct][r] = p;
          rsum += p;
        }
      rsum += __shfl_xor(rsum, 16);
      rsum += __shfl_xor(rsum, 32);
      l_s[r2] += rsum;

      // pack P: lane's 4 regs are k-contiguous -> one b64 store per ct
#pragma unroll
      for (int ct = 0; ct < 4; ++ct) {
        h4v pk = {(_Float16)St[ct][0], (_Float16)St[ct][1],
                  (_Float16)St[ct][2], (_Float16)St[ct][3]};
        if (ct < 2)
          *(h4v*)&PlA[wave][r2 * 16 + lr][ct * 16 + lg * 4] = pk;
        else
          *(h4v*)&PlB[wave][r2 * 16 + lr][(ct - 2) * 16 + lg * 4] = pk;
      }
    }

    // ---- acc^T += V^T P^T : D[d][q], col q=lr lane-local ----
    __builtin_amdgcn_s_setprio(1);
#pragma unroll
    for (int r2 = 0; r2 < 2; ++r2)
#pragma unroll
      for (int c = 0; c < 2; ++c) {
        h8 pa = (c == 0) ? *(const h8*)&PlA[wave][r2 * 16 + lr][lg * 8]
                         : *(const h8*)&PlB[wave][r2 * 16 + lr][lg * 8];
#pragma unroll
        for (int dt = 0; dt < 4; ++dt)
          acc[r2][dt] = mfma16(vb[dt][c], pa, acc[r2][dt]);
      }
    __builtin_amdgcn_s_setprio(0);
  }

  // ---- epilogue: divide by l (lane-local), pack h4, write [B][N][H*64] ----
#pragma unroll
  for (int r2 = 0; r2 < 2; ++r2) {
    float inv = 1.0f / l_s[r2];
    int q = q0 + r2 * 16 + lr;
#pragma unroll
    for (int dt = 0; dt < 4; ++dt) {
      h4v o = {(_Float16)(acc[r2][dt][0] * inv), (_Float16)(acc[r2][dt][1] * inv),
               (_Float16)(acc[r2][dt][2] * inv), (_Float16)(acc[r2][dt][3] * inv)};
      *(h4v*)&aoh[((size_t)(b * SEQ + q)) * DIM_C + h * HD + dt * 16 + lg * 4] = o;
    }
  }
}

// ---------------------------------------------------------------------------
// launch
// ---------------------------------------------------------------------------
extern "C" void kernel_launch(void* const* d_in, const int* in_sizes, int n_in,
                              void* d_out, int out_size, void* d_ws, size_t ws_size,
                              hipStream_t stream) {
  const float* x     = (const float*)d_in[0];
  const float* w_qkv = (const float*)d_in[1];
  const float* w_out = (const float*)d_in[2];
  float* out = (float*)d_out;

  char* w = (char*)d_ws;
  _Float16* xh    = (_Float16*)(w + 0);           //  8 MB  [4096][1024]
  _Float16* wqkvh = (_Float16*)(w + 8388608);     //  6 MB  [3072][1024]
  _Float16* wouth = (_Float16*)(w + 14680064);    //  2 MB  [1024][1024]
  _Float16* qkvh  = (_Float16*)(w + 16777216);    // 24 MB  [4096][3072] (dead after rope)
  _Float16* qhp   = (_Float16*)(w + 41943040);    //  8 MB  [2][16][2048][64]
  _Float16* khp   = (_Float16*)(w + 50331648);    //  8 MB
  _Float16* vhp   = (_Float16*)(w + 58720256);    //  8 MB
  _Float16* aohp  = (_Float16*)(w + 67108864);    //  8 MB  [4096][1024]
  float*    cosT  = (float*)(w + 75497472);       // 256 KB [2048][32]
  float*    sinT  = (float*)(w + 75759616);       // 256 KB
  _Float16* vtp   = (_Float16*)(w + 16777216);    //  8 MB  [2][16][64][2048] (reuses qkvh)

  cvt_kernel<<<1024, 256, 0, stream>>>(x, xh, MTOT * DIM_C / 4);
  cvt_kernel<<<1024, 256, 0, stream>>>(w_qkv, wqkvh, NQKV * DIM_C / 4);
  cvt_kernel<<<512, 256, 0, stream>>>(w_out, wouth, DIM_C * DIM_C / 4);
  rope_table_kernel<<<SEQ * 32 / 256, 256, 0, stream>>>(cosT, sinT);

  gemm_nt<1><<<dim3(NQKV / 128, MTOT / 128), 256, 0, stream>>>(
      xh, wqkvh, (void*)qkvh, MTOT, NQKV, DIM_C);

  rope_apply_kernel<<<MTOT * 3 * NHEAD * 4 / 256, 256, 0, stream>>>(
      qkvh, cosT, sinT, qhp, khp, vhp);

  vtrans_kernel<<<32 * 64, 256, 0, stream>>>(vhp, vtp);   // qkvh region now dead

  attn_kernel<<<32 * (SEQ / 128), 256, 0, stream>>>(qhp, khp, vtp, aohp);

  gemm_nt<0><<<dim3(DIM_C / 128, MTOT / 128), 256, 0, stream>>>(
      aohp, wouth, (void*)out, MTOT, DIM_C, DIM_C);
}